// Round 3
// baseline (173.453 us; speedup 1.0000x reference)
//
#include <hip/hip_runtime.h>

// Problem constants: h[B,G,D], W[G,D,K], out[B,G,K]
#define Gn   100
#define Bn   256
#define Dn   768
#define Kn   128
#define LDP  72   // padded LDS leading dim in shorts (64+8): even bank spread for b128 ops

typedef __attribute__((ext_vector_type(8))) short short8;
typedef __attribute__((ext_vector_type(4))) float f32x4;

// pack two fp32 -> two bf16 (round-to-nearest, ties away) in 3 VALU:
// v_add_u32 x2 + v_perm_b32. 0.5-ulp bound, same as RNE except exact ties.
__device__ inline unsigned pack2(float lo, float hi) {
  union { float f; unsigned u; } a, b; a.f = lo; b.f = hi;
  // result = (hi16(b.u+0x8000) << 16) | hi16(a.u+0x8000)
  return __builtin_amdgcn_perm(b.u + 0x8000u, a.u + 0x8000u, 0x07060302u);
}

// Fully fused grouped GEMM with in-flight L2 norms.
// 64x64 tile / block, BK=64, 4 waves (2x2), mfma_f32_16x16x32_bf16.
// grid (4, 2, 100), block 256. Even/odd register + LDS double buffering:
// prefetch gap = one full BK=64 body (~2x the old gap) to cover HBM latency.
__global__ __launch_bounds__(256) void groupfc_kernel(
    const float* __restrict__ h, const float* __restrict__ W,
    float* __restrict__ out) {
  const int g    = blockIdx.z;
  const int mt   = blockIdx.x;               // 0..3 (rows of 64)
  const int nt   = blockIdx.y;               // 0..1 (cols of 64)
  const int t    = threadIdx.x;
  const int lane = t & 63;
  const int wave = t >> 6;
  const int wm   = wave >> 1, wn = wave & 1; // 2x2 wave grid, 32x32 each

  __shared__ __align__(16) short Alds[2][64 * LDP];  // [m][k] bf16
  __shared__ __align__(16) short Blds[2][64 * LDP];  // [n][k] bf16 (W transposed)
  __shared__ float AssqL[64];                // per-row sum(h^2) over full D
  __shared__ float BssqL[4][64];             // per-col sum(W^2) partials per wave

  f32x4 acc00 = {0.f,0.f,0.f,0.f};
  f32x4 acc01 = acc00, acc10 = acc00, acc11 = acc00;

  // A staging: thread -> (row ar, 16 contiguous d at ac)
  const int ar = t >> 2;
  const int ac = (t & 3) * 16;
  const float* aptr = h + ((size_t)(mt * 64 + ar) * Gn + g) * Dn + ac;
  // B staging: thread -> (col bk, 16 d starting at bd); coalesced across lanes
  const int bk = t & 63;
  const int bd = (t >> 6) * 16;
  const float* bptr = W + (size_t)g * (Dn * Kn) + (size_t)bd * Kn + nt * 64 + bk;

  const int quad = lane >> 4;
  const int koff = quad * 8;                 // A/B fragment: k = quad*8 + j
  const int l15  = lane & 15;
  const int m0   = wm * 32 + l15;
  const int n0   = wn * 32 + l15;

  float assq = 0.f, bssq = 0.f;

  float4 ca[4]; float cb[16];                // even-chunk registers
  float4 pa[4]; float pb[16];                // odd-chunk registers

  auto load_chunk = [&](int kc, float4 (&A)[4], float (&Bv)[16]) {
    const int d0 = kc * 64;
    const float* ap = aptr + d0;
#pragma unroll
    for (int i = 0; i < 4; ++i) A[i] = *(const float4*)(ap + i * 4);
#pragma unroll
    for (int i = 0; i < 16; ++i) Bv[i] = bptr[(size_t)(d0 + i) * Kn];
  };

  auto stage_mfma = [&](int buf, const float4 (&A)[4], const float (&Bv)[16]) {
    // fp32 sum-of-squares (pre-quantization) for the norms
    float as = 0.f;
#pragma unroll
    for (int i = 0; i < 4; ++i)
      as += A[i].x*A[i].x + A[i].y*A[i].y + A[i].z*A[i].z + A[i].w*A[i].w;
    assq += as;
    float bs = 0.f;
#pragma unroll
    for (int i = 0; i < 16; ++i) bs += Bv[i] * Bv[i];
    bssq += bs;

    // pack 16 fp32 -> 16 bf16 (8 dwords) and store as two b128 per array
    uint4 ap0, ap1;
    ap0.x = pack2(A[0].x, A[0].y); ap0.y = pack2(A[0].z, A[0].w);
    ap0.z = pack2(A[1].x, A[1].y); ap0.w = pack2(A[1].z, A[1].w);
    ap1.x = pack2(A[2].x, A[2].y); ap1.y = pack2(A[2].z, A[2].w);
    ap1.z = pack2(A[3].x, A[3].y); ap1.w = pack2(A[3].z, A[3].w);
    *(uint4*)&Alds[buf][ar * LDP + ac]     = ap0;
    *(uint4*)&Alds[buf][ar * LDP + ac + 8] = ap1;

    uint4 bp0, bp1;
    bp0.x = pack2(Bv[0],  Bv[1]);  bp0.y = pack2(Bv[2],  Bv[3]);
    bp0.z = pack2(Bv[4],  Bv[5]);  bp0.w = pack2(Bv[6],  Bv[7]);
    bp1.x = pack2(Bv[8],  Bv[9]);  bp1.y = pack2(Bv[10], Bv[11]);
    bp1.z = pack2(Bv[12], Bv[13]); bp1.w = pack2(Bv[14], Bv[15]);
    *(uint4*)&Blds[buf][bk * LDP + bd]     = bp0;
    *(uint4*)&Blds[buf][bk * LDP + bd + 8] = bp1;

    __syncthreads();                         // single barrier per BK-step

#pragma unroll
    for (int kk = 0; kk < 2; ++kk) {
      const int o = kk * 32 + koff;
      short8 af0 = *(const short8*)&Alds[buf][m0 * LDP + o];
      short8 af1 = *(const short8*)&Alds[buf][(m0 + 16) * LDP + o];
      short8 bf0 = *(const short8*)&Blds[buf][n0 * LDP + o];
      short8 bf1 = *(const short8*)&Blds[buf][(n0 + 16) * LDP + o];
      acc00 = __builtin_amdgcn_mfma_f32_16x16x32_bf16(af0, bf0, acc00, 0, 0, 0);
      acc01 = __builtin_amdgcn_mfma_f32_16x16x32_bf16(af0, bf1, acc01, 0, 0, 0);
      acc10 = __builtin_amdgcn_mfma_f32_16x16x32_bf16(af1, bf0, acc10, 0, 0, 0);
      acc11 = __builtin_amdgcn_mfma_f32_16x16x32_bf16(af1, bf1, acc11, 0, 0, 0);
    }
  };

  // ---- pipelined main loop: 12 BK=64 chunks, even/odd register buffers ----
  load_chunk(0, ca, cb);
  for (int kc = 0; kc < 12; kc += 2) {
    load_chunk(kc + 1, pa, pb);              // prefetch odd chunk
    stage_mfma(0, ca, cb);                   // consume even chunk
    if (kc + 2 < 12) load_chunk(kc + 2, ca, cb);  // prefetch next even chunk
    stage_mfma(1, pa, pb);                   // consume odd chunk
  }

  // ---- block-reduce the norms ----
  assq += __shfl_xor(assq, 1);               // 4 threads share row ar
  assq += __shfl_xor(assq, 2);
  if ((t & 3) == 0) AssqL[ar] = assq;
  BssqL[wave][bk] = bssq;                    // 4 waves share col bk
  __syncthreads();

  // ---- epilogue: scale by 1/max(||h_row||,eps) * 1/max(||w_col||,eps) ----
  // C/D layout: col = lane&15, row = quad*4 + reg
  const float ws0 = BssqL[0][n0] + BssqL[1][n0] + BssqL[2][n0] + BssqL[3][n0];
  const float ws1 = BssqL[0][n0+16] + BssqL[1][n0+16] + BssqL[2][n0+16] + BssqL[3][n0+16];
  const float wi0 = 1.0f / fmaxf(sqrtf(ws0), 1e-12f);
  const float wi1 = 1.0f / fmaxf(sqrtf(ws1), 1e-12f);

#pragma unroll
  for (int mi = 0; mi < 2; ++mi) {
#pragma unroll
    for (int r = 0; r < 4; ++r) {
      const int lr  = wm * 32 + mi * 16 + quad * 4 + r;   // local row in tile
      const float hs = 1.0f / fmaxf(sqrtf(AssqL[lr]), 1e-12f);
      const float v0 = (mi ? acc10[r] : acc00[r]) * hs * wi0;
      const float v1 = (mi ? acc11[r] : acc01[r]) * hs * wi1;
      const int row = mt * 64 + lr;
      const size_t ob = ((size_t)row * Gn + g) * Kn + nt * 64;
      out[ob + wn * 32 + l15]      = v0;
      out[ob + wn * 32 + l15 + 16] = v1;
    }
  }
}

extern "C" void kernel_launch(void* const* d_in, const int* in_sizes, int n_in,
                              void* d_out, int out_size, void* d_ws, size_t ws_size,
                              hipStream_t stream) {
  const float* h = (const float*)d_in[0];          // [B,G,D]
  const float* W = (const float*)d_in[1];          // [G,D,K]
  float* out = (float*)d_out;                      // [B,G,K]
  hipLaunchKernelGGL(groupfc_kernel, dim3(4, 2, Gn), dim3(256), 0, stream, h, W, out);
}